// Round 1
// baseline (218.346 us; speedup 1.0000x reference)
//
#include <hip/hip_runtime.h>
#include <stdint.h>

#define NTOK 16384
#define CDIM 1024
#define DHEAD 256

typedef short s16x8 __attribute__((ext_vector_type(8)));
typedef float f32x4 __attribute__((ext_vector_type(4)));

static __device__ __forceinline__ unsigned short f2bf(float f) {
    union { float f; unsigned u; } x; x.f = f;
    unsigned r = (x.u + 0x7fffu + ((x.u >> 16) & 1u)) >> 16;
    return (unsigned short)r;
}

// ---------------------------------------------------------------------------
// Kernel 1: partial Gram matrices G[de][e] = sum_n q[b,n,h*256+de]*k[b,n,h*256+e]
// over an n-chunk, plus per-channel partial sums of q and k.
// grid: 8*nchunk blocks, block: 512 threads (8 waves).
// LDS: q,k chunk slice staged transposed-to-[ch][n] as bf16, 16B-slot XOR swizzle.
// ---------------------------------------------------------------------------
__global__ __launch_bounds__(512, 2)
void k_gram(const float* __restrict__ q, const float* __restrict__ k,
            float* __restrict__ Gpart, float* __restrict__ Spart, int nchunk)
{
    __shared__ __align__(16) unsigned short lq[DHEAD * 64];
    __shared__ __align__(16) unsigned short lk[DHEAD * 64];

    const int t     = threadIdx.x;
    const int bh    = blockIdx.x & 7;
    const int chunk = blockIdx.x >> 3;
    const int b     = bh >> 2, h = bh & 3;
    const int rows  = NTOK / nchunk;
    const int n0    = chunk * rows;

    const int ch   = t & 255;
    const int half = t >> 8;
    const int lane = t & 63;
    const int w    = t >> 6;
    const int de0  = (w >> 1) * 64;   // 4 row groups of 64
    const int e0   = (w & 1) * 128;   // 2 col groups of 128

    const size_t base = ((size_t)b * NTOK + n0) * CDIM + (size_t)h * DHEAD + ch;
    const float* qp = q + base;
    const float* kp = k + base;

    float sq = 0.f, sk = 0.f;
    f32x4 acc[4][8];
#pragma unroll
    for (int r = 0; r < 4; ++r)
#pragma unroll
        for (int c = 0; c < 8; ++c) acc[r][c] = (f32x4){0.f, 0.f, 0.f, 0.f};

    for (int nb = 0; nb < rows; nb += 64) {
        // ---- stage 64 n-rows of q,k transposed to [ch][n] bf16 in LDS ----
#pragma unroll
        for (int i = 0; i < 8; ++i) {
            const int quad = half + 2 * i;          // 0..15
            const int nl   = quad * 4;              // 0..60
            const int slot = nl >> 3;               // 0..7
            const int sidx = ch * 64 + ((slot ^ (ch & 7)) * 8) + (nl & 7);

            const float* qq = qp + (size_t)(nb + nl) * CDIM;
            float a0 = qq[0], a1 = qq[CDIM], a2 = qq[2 * CDIM], a3 = qq[3 * CDIM];
            sq += (a0 + a1) + (a2 + a3);
            *reinterpret_cast<ushort4*>(&lq[sidx]) =
                make_ushort4(f2bf(a0), f2bf(a1), f2bf(a2), f2bf(a3));

            const float* kq = kp + (size_t)(nb + nl) * CDIM;
            float b0 = kq[0], b1 = kq[CDIM], b2 = kq[2 * CDIM], b3 = kq[3 * CDIM];
            sk += (b0 + b1) + (b2 + b3);
            *reinterpret_cast<ushort4*>(&lk[sidx]) =
                make_ushort4(f2bf(b0), f2bf(b1), f2bf(b2), f2bf(b3));
        }
        __syncthreads();

        // ---- 2 k-steps of 32 n each ----
#pragma unroll
        for (int kk = 0; kk < 2; ++kk) {
            s16x8 af[4], bfr[8];
#pragma unroll
            for (int r = 0; r < 4; ++r) {
                const int row  = de0 + r * 16 + (lane & 15);
                const int slot = kk * 4 + (lane >> 4);
                af[r] = *reinterpret_cast<const s16x8*>(&lq[row * 64 + ((slot ^ (row & 7)) * 8)]);
            }
#pragma unroll
            for (int c = 0; c < 8; ++c) {
                const int row  = e0 + c * 16 + (lane & 15);
                const int slot = kk * 4 + (lane >> 4);
                bfr[c] = *reinterpret_cast<const s16x8*>(&lk[row * 64 + ((slot ^ (row & 7)) * 8)]);
            }
#pragma unroll
            for (int r = 0; r < 4; ++r)
#pragma unroll
                for (int c = 0; c < 8; ++c)
                    acc[r][c] = __builtin_amdgcn_mfma_f32_16x16x32_bf16(af[r], bfr[c], acc[r][c], 0, 0, 0);
        }
        __syncthreads();
    }

    // ---- write partial G (fp32) ----
    float* gp = Gpart + (size_t)(bh * nchunk + chunk) * 65536;
#pragma unroll
    for (int r = 0; r < 4; ++r) {
        const int de_b = de0 + r * 16 + (lane >> 4) * 4;
#pragma unroll
        for (int c = 0; c < 8; ++c) {
            const int e = e0 + c * 16 + (lane & 15);
#pragma unroll
            for (int reg = 0; reg < 4; ++reg)
                gp[(size_t)(de_b + reg) * 256 + e] = acc[r][c][reg];
        }
    }
    // ---- write partial channel sums ----
    float* sp = Spart + (size_t)((bh * nchunk + chunk) * 2 + half) * 512;
    sp[ch]       = sq;
    sp[256 + ch] = sk;
}

// ---------------------------------------------------------------------------
// Kernel 2: reduce G partials across chunks. grid 8*64, block 256.
// ---------------------------------------------------------------------------
__global__ __launch_bounds__(256)
void k_reduceG(const float* __restrict__ Gpart, float* __restrict__ Gred, int nchunk)
{
    const int t   = threadIdx.x;
    const int bh  = blockIdx.x >> 6;
    const int seg = blockIdx.x & 63;
    const size_t base = (size_t)bh * nchunk * 65536;
#pragma unroll
    for (int i = 0; i < 4; ++i) {
        const int idx = seg * 1024 + i * 256 + t;
        float s = 0.f;
        for (int c = 0; c < nchunk; ++c) s += Gpart[base + (size_t)c * 65536 + idx];
        Gred[(size_t)bh * 65536 + idx] = s;
    }
}

// ---------------------------------------------------------------------------
// Kernel 3: build scores from G + rank-1 corrections, softmax both branches,
// emit combined W (bf16) and beta. grid 8*8 (bh x rowgroup), block 256.
// ---------------------------------------------------------------------------
__global__ __launch_bounds__(256)
void k_scores(const float* __restrict__ Gred, const float* __restrict__ Spart,
              const float* __restrict__ wqg, const float* __restrict__ bqg,
              const float* __restrict__ wkg, const float* __restrict__ bkg,
              const float* __restrict__ wvg, const float* __restrict__ bvg,
              const float* __restrict__ wql, const float* __restrict__ bql,
              const float* __restrict__ wkl, const float* __restrict__ bkl,
              const float* __restrict__ wvl, const float* __restrict__ bvl,
              const float* __restrict__ wp,  const float* __restrict__ bp,
              unsigned short* __restrict__ Wm, float* __restrict__ beta, int nchunk)
{
    __shared__ float sSq[256], sSk[256];
    const int t  = threadIdx.x;
    const int bh = blockIdx.x >> 3;
    const int rg = blockIdx.x & 7;
    const int h  = bh & 3;

    // reduce channel sums
    float aq = 0.f, ak = 0.f;
    for (int c = 0; c < nchunk; ++c)
        for (int hf = 0; hf < 2; ++hf) {
            const float* sp = Spart + (size_t)((bh * nchunk + c) * 2 + hf) * 512;
            aq += sp[t];
            ak += sp[256 + t];
        }
    sSq[t] = aq; sSk[t] = ak;
    __syncthreads();

    const int w = t >> 6, lane = t & 63;
    const float* gbh = Gred + (size_t)bh * 65536;
    const float scale = 0.03125f;

    for (int i = 0; i < 8; ++i) {
        const int de = rg * 32 + i * 4 + w;
        const int cd = h * DHEAD + de;
        float g[4];
#pragma unroll
        for (int j = 0; j < 4; ++j) g[j] = gbh[(size_t)de * 256 + j * 64 + lane];
        const float sqv = sSq[de];

        float wrow[4] = {0.f, 0.f, 0.f, 0.f};
        float bacc = 0.f;
#pragma unroll
        for (int br = 0; br < 2; ++br) {
            const float* wq = br ? wql : wqg;  const float* bq = br ? bql : bqg;
            const float* wk = br ? wkl : wkg;  const float* bk = br ? bkl : bkg;
            const float* wv = br ? wvl : wvg;  const float* bv = br ? bvl : bvg;
            const float wqv = wq[cd], bqv = bq[cd];

            float s[4], m = -1e30f;
#pragma unroll
            for (int j = 0; j < 4; ++j) {
                const int e = j * 64 + lane, ce = h * DHEAD + e;
                const float wkv = wk[ce], bkv = bk[ce];
                s[j] = scale * (wqv * wkv * g[j] + wqv * bkv * sqv
                                + bqv * wkv * sSk[e] + bqv * bkv * 16384.0f);
                m = fmaxf(m, s[j]);
            }
            for (int off = 32; off; off >>= 1) m = fmaxf(m, __shfl_xor(m, off));
            float p[4], sum = 0.f;
#pragma unroll
            for (int j = 0; j < 4; ++j) { p[j] = __expf(s[j] - m); sum += p[j]; }
            for (int off = 32; off; off >>= 1) sum += __shfl_xor(sum, off);
            const float inv = 1.f / sum;
#pragma unroll
            for (int j = 0; j < 4; ++j) {
                const int ce = h * DHEAD + j * 64 + lane;
                const float a = p[j] * inv;
                wrow[j] += a * wv[ce];
                bacc    += a * bv[ce];
            }
        }
        const float wp2 = 2.f * wp[cd];
#pragma unroll
        for (int j = 0; j < 4; ++j)
            Wm[(size_t)bh * 65536 + (size_t)de * 256 + j * 64 + lane] = f2bf(wp2 * wrow[j]);
        for (int off = 32; off; off >>= 1) bacc += __shfl_xor(bacc, off);
        if (lane == 0) beta[bh * 256 + de] = wp2 * bacc + bp[cd];
    }
}

// ---------------------------------------------------------------------------
// Kernel 4: Out[n][dd] = sum_e W[dd][e]*v[n][ce] + beta[dd].
// grid 8*128 (bh x n-tile of 128), block 256 (4 waves, each 64n x 128dd).
// v tile staged to LDS bf16 (swizzled); W frags read from global (L2-hot).
// ---------------------------------------------------------------------------
__global__ __launch_bounds__(256, 2)
void k_out(const float* __restrict__ v, const unsigned short* __restrict__ Wm,
           const float* __restrict__ beta, float* __restrict__ out)
{
    __shared__ __align__(16) unsigned short lv[128 * 256];
    const int t    = threadIdx.x;
    const int bh   = blockIdx.x & 7;
    const int tile = blockIdx.x >> 3;
    const int b    = bh >> 2, h = bh & 3;
    const int n0   = tile * 128;

    // ---- stage v tile (128 x 256) as bf16 ----
#pragma unroll
    for (int i = 0; i < 16; ++i) {
        const int sf = i * 256 + t;
        const int n  = sf >> 5, s = sf & 31;
        const float* vp = v + ((size_t)b * NTOK + n0 + n) * CDIM + (size_t)h * DHEAD + s * 8;
        const float4 v0 = *reinterpret_cast<const float4*>(vp);
        const float4 v1 = *reinterpret_cast<const float4*>(vp + 4);
        const int idx = n * 256 + ((s ^ (n & 7)) * 8);
        *reinterpret_cast<ushort4*>(&lv[idx])     = make_ushort4(f2bf(v0.x), f2bf(v0.y), f2bf(v0.z), f2bf(v0.w));
        *reinterpret_cast<ushort4*>(&lv[idx + 4]) = make_ushort4(f2bf(v1.x), f2bf(v1.y), f2bf(v1.z), f2bf(v1.w));
    }
    __syncthreads();

    const int w = t >> 6, lane = t & 63;
    const int nw  = (w >> 1) * 64;
    const int dd0 = (w & 1) * 128;
    const unsigned short* Wg = Wm + (size_t)bh * 65536;

    f32x4 acc[4][8];
#pragma unroll
    for (int r = 0; r < 4; ++r)
#pragma unroll
        for (int c = 0; c < 8; ++c) acc[r][c] = (f32x4){0.f, 0.f, 0.f, 0.f};

#pragma unroll
    for (int ks = 0; ks < 8; ++ks) {
        const int e0 = ks * 32;
        s16x8 af[4], bfr[8];
#pragma unroll
        for (int r = 0; r < 4; ++r) {
            const int n  = nw + r * 16 + (lane & 15);
            const int sg = (e0 >> 3) + (lane >> 4);
            af[r] = *reinterpret_cast<const s16x8*>(&lv[n * 256 + ((sg ^ (n & 7)) * 8)]);
        }
#pragma unroll
        for (int c = 0; c < 8; ++c) {
            const int dd = dd0 + c * 16 + (lane & 15);
            const int e  = e0 + (lane >> 4) * 8;
            bfr[c] = *reinterpret_cast<const s16x8*>(Wg + (size_t)dd * 256 + e);
        }
#pragma unroll
        for (int r = 0; r < 4; ++r)
#pragma unroll
            for (int c = 0; c < 8; ++c)
                acc[r][c] = __builtin_amdgcn_mfma_f32_16x16x32_bf16(af[r], bfr[c], acc[r][c], 0, 0, 0);
    }

    float betar[8];
#pragma unroll
    for (int c = 0; c < 8; ++c) betar[c] = beta[bh * 256 + dd0 + c * 16 + (lane & 15)];

#pragma unroll
    for (int r = 0; r < 4; ++r)
#pragma unroll
        for (int c = 0; c < 8; ++c) {
            const int dd = dd0 + c * 16 + (lane & 15);
#pragma unroll
            for (int reg = 0; reg < 4; ++reg) {
                const int n = nw + r * 16 + (lane >> 4) * 4 + reg;
                out[((size_t)b * NTOK + n0 + n) * CDIM + (size_t)h * DHEAD + dd] =
                    acc[r][c][reg] + betar[c];
            }
        }
}

// ---------------------------------------------------------------------------
extern "C" void kernel_launch(void* const* d_in, const int* in_sizes, int n_in,
                              void* d_out, int out_size, void* d_ws, size_t ws_size,
                              hipStream_t stream)
{
    const float* q = (const float*)d_in[0];
    const float* k = (const float*)d_in[1];
    const float* v = (const float*)d_in[2];
    const float* wgt[14];
    for (int i = 0; i < 14; ++i) wgt[i] = (const float*)d_in[3 + i];
    float* out = (float*)d_out;

    // choose split-K chunk count to fit workspace (deterministic given ws_size)
    int nchunk = 32;
    while (nchunk > 1) {
        size_t need = (size_t)8 * nchunk * 65536 * 4   // Gpart
                    + (size_t)8 * 65536 * 4            // Gred
                    + (size_t)8 * nchunk * 1024 * 4    // Spart
                    + (size_t)8 * 65536 * 2            // W bf16
                    + (size_t)8 * 256 * 4 + 1024;      // beta + slack
        if (need <= ws_size) break;
        nchunk >>= 1;
    }

    char* p = (char*)d_ws;
    float* Gpart = (float*)p;          p += (size_t)8 * nchunk * 65536 * 4;
    float* Gred  = (float*)p;          p += (size_t)8 * 65536 * 4;
    float* Spart = (float*)p;          p += (size_t)8 * nchunk * 1024 * 4;
    unsigned short* Wm = (unsigned short*)p; p += (size_t)8 * 65536 * 2;
    float* beta  = (float*)p;

    k_gram<<<dim3(8 * nchunk), dim3(512), 0, stream>>>(q, k, Gpart, Spart, nchunk);
    k_reduceG<<<dim3(8 * 64), dim3(256), 0, stream>>>(Gpart, Gred, nchunk);
    k_scores<<<dim3(8 * 8), dim3(256), 0, stream>>>(
        Gred, Spart,
        wgt[0], wgt[1], wgt[2], wgt[3], wgt[4], wgt[5],
        wgt[6], wgt[7], wgt[8], wgt[9], wgt[10], wgt[11],
        wgt[12], wgt[13], Wm, beta, nchunk);
    k_out<<<dim3(8 * 128), dim3(256), 0, stream>>>(v, Wm, beta, out);
}